// Round 2
// baseline (7469.711 us; speedup 1.0000x reference)
//
#include <hip/hip_runtime.h>
#include <hip/hip_bf16.h>
#include <math.h>

// Problem constants (from reference)
#define N_NODES 100000
#define F_IN    256
#define HID     128
#define NCLS    32
#define NEDGES  1600000
#define EPS_C   0.1f
#define GAMMA_C 0.1f

typedef __attribute__((ext_vector_type(8))) short short8;   // 8 bf16 = 4 VGPRs (MFMA A/B frag)
typedef __attribute__((ext_vector_type(4))) float floatx4;  // MFMA C/D frag

__device__ __forceinline__ float bf2f(unsigned short u) {
    union { unsigned int u; float f; } c;
    c.u = ((unsigned int)u) << 16;
    return c.f;
}
__device__ __forceinline__ unsigned short f2bf(float f) {
    union { float f; unsigned int u; } c; c.f = f;
    unsigned int u = c.u;
    u += 0x7FFFu + ((u >> 16) & 1u);   // round-to-nearest-even
    return (unsigned short)(u >> 16);
}

// Polymorphic scalar load/store: md=1 -> buffer is f32, md=0 -> bf16
__device__ __forceinline__ float ldf(const void* p, size_t i, int md) {
    return md ? ((const float*)p)[i] : bf2f(((const unsigned short*)p)[i]);
}
__device__ __forceinline__ short8 ld8(const void* p, size_t i, int md) {
    if (md) {
        const float* q = (const float*)p + i;
        short8 r;
#pragma unroll
        for (int j = 0; j < 8; ++j) r[j] = (short)f2bf(q[j]);
        return r;
    }
    return *(const short8*)((const unsigned short*)p + i);
}

// ---------------------------------------------------------------- dtype probe
// f32 data read as shorts: even indices are mantissa-low halves -> random
// exponents -> ~45% of |bf2f| exceed 1e4. bf16 data: values ~N(0,1), none do.
__global__ void k_detect(const unsigned short* __restrict__ x, int* __restrict__ mode) {
    __shared__ int cnt;
    if (threadIdx.x == 0) cnt = 0;
    __syncthreads();
    float v = fabsf(bf2f(x[2 * threadIdx.x]));
    if (v > 1e4f || !isfinite(v)) atomicAdd(&cnt, 1);
    __syncthreads();
    if (threadIdx.x == 0) *mode = (cnt >= 8) ? 1 : 0;
}

// ---------------------------------------------------------------- utility
__global__ void k_zero(float* __restrict__ p, int n) {
    int i = blockIdx.x * blockDim.x + threadIdx.x;
    int stride = gridDim.x * blockDim.x;
    for (; i < n; i += stride) p[i] = 0.0f;
}

__global__ void k_deg(const int* __restrict__ col, float* __restrict__ deg, int e) {
    int i = blockIdx.x * blockDim.x + threadIdx.x;
    if (i < e) atomicAdd(&deg[col[i]], 1.0f);
}

// dinv[i] = rsqrt(deg[i] + 1)  (self-loop adds 1)
__global__ void k_dinv(float* __restrict__ deg, int n) {
    int i = blockIdx.x * blockDim.x + threadIdx.x;
    if (i < n) deg[i] = rsqrtf(deg[i] + 1.0f);
}

// aw = W - W^T - gamma*I  (row-major [d,d], bf16 out; W is an input -> poly)
__global__ void k_aw(const void* __restrict__ W, unsigned short* __restrict__ aw,
                     const int* __restrict__ dmode, int d) {
    int idx = blockIdx.x * blockDim.x + threadIdx.x;
    if (idx >= d * d) return;
    int md = dmode[0];
    int n = idx / d, k = idx - n * d;
    float v = ldf(W, n * d + k, md) - ldf(W, k * d + n, md) - ((n == k) ? GAMMA_C : 0.0f);
    aw[idx] = f2bf(v);
}

// ---------------------------------------------------------------- GEMM
// C[M,NC] = A[M,K] @ B[NC,K]^T, fp32 acc, bf16 out (internal).
// One wave per 16-row tile, 4 waves (64 rows) per block, NT = NC/16 col tiles.
// EPI: 0 = relu(acc+bias), 1 = acc, 2 = acc+bias,
//      3 = ASC: h + EPS*tanh(acc + agg + dinv^2*xw + bias)  (requires K==NC)
// APOLY/BPOLY: whether A/B are harness inputs (runtime-dtype) or internal bf16.
// NOTE: Cout may alias xw (per-element read-before-write in same thread).
template<int K, int NC, int EPI, bool APOLY, bool BPOLY>
__global__ __launch_bounds__(256) void k_gemm(
    const void* A, const void* B, const void* bias,
    unsigned short* Cout,
    const float* agg, const unsigned short* xw, const float* dinv,
    const int* dmode, int M)
{
    constexpr int NT = NC / 16;
    const int md = dmode[0];
    const int wave = threadIdx.x >> 6;
    const int lane = threadIdx.x & 63;
    const int l15  = lane & 15;
    const int quad = lane >> 4;
    const int row_base = blockIdx.x * 64 + wave * 16;
    if (row_base >= M) return;

    int am = row_base + l15;
    if (am > M - 1) am = M - 1;           // clamp (dup read only, store guarded)

    floatx4 acc[NT];
#pragma unroll
    for (int t = 0; t < NT; ++t) acc[t] = (floatx4){0.f, 0.f, 0.f, 0.f};

#pragma unroll
    for (int kk = 0; kk < K; kk += 32) {
        short8 a = APOLY ? ld8(A, (size_t)am * K + kk + quad * 8, md)
                         : *(const short8*)((const unsigned short*)A + (size_t)am * K + kk + quad * 8);
#pragma unroll
        for (int t = 0; t < NT; ++t) {
            size_t bi = (size_t)(t * 16 + l15) * K + kk + quad * 8;
            short8 b = BPOLY ? ld8(B, bi, md)
                             : *(const short8*)((const unsigned short*)B + bi);
            acc[t] = __builtin_amdgcn_mfma_f32_16x16x32_bf16(a, b, acc[t], 0, 0, 0);
        }
    }

    // C/D layout: col = lane&15, row = quad*4 + reg  [m89-verified]
#pragma unroll
    for (int reg = 0; reg < 4; ++reg) {
        int rr = row_base + quad * 4 + reg;
        if (rr >= M) continue;
#pragma unroll
        for (int t = 0; t < NT; ++t) {
            int col = t * 16 + l15;
            float v = acc[t][reg];
            if (EPI == 0) {
                v += ldf(bias, col, md);
                v = v > 0.0f ? v : 0.0f;
            } else if (EPI == 2) {
                v += ldf(bias, col, md);
            } else if (EPI == 3) {
                float dv = dinv[rr];
                float z = v + agg[(size_t)rr * NC + col]
                            + dv * dv * bf2f(xw[(size_t)rr * NC + col])
                            + ldf(bias, col, md);
                v = bf2f(((const unsigned short*)A)[(size_t)rr * K + col]) + EPS_C * tanhf(z);
            }
            Cout[(size_t)rr * NC + col] = f2bf(v);
        }
    }
}

// ---------------------------------------------------------------- scatter
// agg[col[e]] += dinv[row]*dinv[col] * xw[row]  (D features, D/8 threads/edge)
template<int D>
__global__ __launch_bounds__(256) void k_scatter(
    const int* __restrict__ row, const int* __restrict__ col,
    const unsigned short* __restrict__ xw, const float* __restrict__ dinv,
    float* __restrict__ agg, int e)
{
    constexpr int TPE = D / 8;
    constexpr int EPB = 256 / TPE;
    int eidx = blockIdx.x * EPB + threadIdx.x / TPE;
    int f = (threadIdx.x % TPE) * 8;
    if (eidx >= e) return;
    int r = row[eidx], c = col[eidx];
    float nrm = dinv[r] * dinv[c];
    short8 v8 = *(const short8*)(xw + (size_t)r * D + f);
    float* dst = agg + (size_t)c * D + f;
    const unsigned short* vs = (const unsigned short*)&v8;
#pragma unroll
    for (int j = 0; j < 8; ++j)
        atomicAdd(dst + j, nrm * bf2f(vs[j]));
}

// ---------------------------------------------------------------- softmax
__global__ void k_logsoftmax(const unsigned short* __restrict__ h,
                             void* __restrict__ out,
                             const int* __restrict__ dmode, int n)
{
    int i = blockIdx.x * blockDim.x + threadIdx.x;
    if (i >= n) return;
    int md = dmode[0];
    float v[NCLS];
    float m = -1e30f;
#pragma unroll
    for (int j = 0; j < NCLS; ++j) { v[j] = bf2f(h[(size_t)i * NCLS + j]); m = fmaxf(m, v[j]); }
    float s = 0.0f;
#pragma unroll
    for (int j = 0; j < NCLS; ++j) s += expf(v[j] - m);
    float ls = m + logf(s);
#pragma unroll
    for (int j = 0; j < NCLS; ++j) {
        float r = v[j] - ls;
        if (md) ((float*)out)[(size_t)i * NCLS + j] = r;
        else    ((unsigned short*)out)[(size_t)i * NCLS + j] = f2bf(r);
    }
}

// ---------------------------------------------------------------- launch
extern "C" void kernel_launch(void* const* d_in, const int* in_sizes, int n_in,
                              void* d_out, int out_size, void* d_ws, size_t ws_size,
                              hipStream_t stream)
{
    const void* x      = d_in[0];    // [N,256]
    const void* lin1_w = d_in[1];    // [128,256]
    const void* lin1_b = d_in[2];    // [128]
    const void* lin2_w = d_in[3];    // [32,128]
    const void* lin2_b = d_in[4];    // [32]
    const void* W1     = d_in[5];    // [128,128]
    const void* phi1w  = d_in[6];    // [128,128]
    const void* b1     = d_in[7];    // [128]
    const void* W2     = d_in[8];    // [32,32]
    const void* phi2w  = d_in[9];    // [32,32]
    const void* b2     = d_in[10];   // [32]
    const int* eidx    = (const int*)d_in[11];   // [2,E]
    const int* erow = eidx;
    const int* ecol = eidx + NEDGES;

    // Workspace layout (high-water ~103 MB):
    //   [0, 400000)      dinv f32 (doubles as deg)
    //   [400000, +4)     dtype mode flag
    //   [401408, +32KB)  aw1 bf16 128x128
    //   [435200, +2KB)   aw2 bf16 32x32
    //   [524288, 25.6MB) h1 bf16 [N,128]      (layer2: h3 [N,32])
    //   [+25.6MB)        xw1 bf16 [N,128] -> h2 written in-place (EPI=3 aliases
    //                    Cout onto xw; per-thread read-before-write). layer2: xw2
    //   [+51.2MB)        agg1 f32 [N,128]     (layer2: agg2 f32 [N,32], then
    //                    h4 bf16 at +12.8MB inside this region)
    char* ws = (char*)d_ws;
    float* dinv          = (float*)ws;
    int*   dmode         = (int*)(ws + 400000);
    unsigned short* aw1  = (unsigned short*)(ws + 401408);
    unsigned short* aw2  = (unsigned short*)(ws + 435200);
    size_t off = 524288;
    unsigned short* h1   = (unsigned short*)(ws + off); off += (size_t)N_NODES * HID * 2;
    unsigned short* xw1  = (unsigned short*)(ws + off); off += (size_t)N_NODES * HID * 2;
    float* agg1          = (float*)(ws + off);
    unsigned short* h2   = xw1;            // in-place (EPI=3 read-before-write)
    unsigned short* h3   = h1;             // h1 dead after layer-1 EPI=3
    unsigned short* xw2  = xw1;            // h2 dead after lin2 gemm
    float* agg2          = agg1;
    unsigned short* h4   = (unsigned short*)((char*)agg1 + (size_t)N_NODES * NCLS * 4);

    const int GB = 256;
    k_detect<<<1, 256, 0, stream>>>((const unsigned short*)x, dmode);
    // degree + norm
    k_zero<<<256, GB, 0, stream>>>(dinv, N_NODES);
    k_deg<<<(NEDGES + GB - 1) / GB, GB, 0, stream>>>(ecol, dinv, NEDGES);
    k_dinv<<<(N_NODES + GB - 1) / GB, GB, 0, stream>>>(dinv, N_NODES);
    // antisymmetric weights
    k_aw<<<(HID * HID + GB - 1) / GB, GB, 0, stream>>>(W1, aw1, dmode, HID);
    k_aw<<<(NCLS * NCLS + GB - 1) / GB, GB, 0, stream>>>(W2, aw2, dmode, NCLS);

    const int gRows = (N_NODES + 63) / 64;
    // h1 = relu(x @ lin1_w.T + lin1_b)
    k_gemm<256, 128, 0, true, true><<<gRows, 256, 0, stream>>>(
        x, lin1_w, lin1_b, h1, nullptr, nullptr, nullptr, dmode, N_NODES);
    // xw1 = h1 @ phi1_w.T
    k_gemm<128, 128, 1, false, true><<<gRows, 256, 0, stream>>>(
        h1, phi1w, nullptr, xw1, nullptr, nullptr, nullptr, dmode, N_NODES);
    // agg1 = scatter(norm * xw1[row] -> col)
    k_zero<<<2048, GB, 0, stream>>>(agg1, N_NODES * HID);
    k_scatter<128><<<(NEDGES * 16 + 255) / 256, 256, 0, stream>>>(erow, ecol, xw1, dinv, agg1, NEDGES);
    // h2 = h1 + EPS*tanh(h1@aw1.T + agg1 + dinv^2*xw1 + b1)   (h2 aliases xw1)
    k_gemm<128, 128, 3, false, false><<<gRows, 256, 0, stream>>>(
        h1, aw1, b1, h2, agg1, xw1, dinv, dmode, N_NODES);
    // h3 = h2 @ lin2_w.T + lin2_b   (h3 overwrites h1 region; h1 dead)
    k_gemm<128, 32, 2, false, true><<<gRows, 256, 0, stream>>>(
        h2, lin2_w, lin2_b, h3, nullptr, nullptr, nullptr, dmode, N_NODES);
    // xw2 = h3 @ phi2_w.T            (xw2 overwrites h2 region; h2 dead)
    k_gemm<32, 32, 1, false, true><<<gRows, 256, 0, stream>>>(
        h3, phi2w, nullptr, xw2, nullptr, nullptr, nullptr, dmode, N_NODES);
    // agg2 = scatter(norm * xw2[row] -> col)
    k_zero<<<1024, GB, 0, stream>>>(agg2, N_NODES * NCLS);
    k_scatter<32><<<(NEDGES * 4 + 255) / 256, 256, 0, stream>>>(erow, ecol, xw2, dinv, agg2, NEDGES);
    // h4 = h3 + EPS*tanh(h3@aw2.T + agg2 + dinv^2*xw2 + b2)
    k_gemm<32, 32, 3, false, false><<<gRows, 256, 0, stream>>>(
        h3, aw2, b2, h4, agg2, xw2, dinv, dmode, N_NODES);
    // out = log_softmax(h4)
    k_logsoftmax<<<(N_NODES + GB - 1) / GB, GB, 0, stream>>>(h4, d_out, dmode, N_NODES);
}

// Round 3
// 873.139 us; speedup vs baseline: 8.5550x; 8.5550x over previous
//
#include <hip/hip_runtime.h>
#include <hip/hip_bf16.h>
#include <math.h>

// Problem constants (from reference)
#define N_NODES 100000
#define F_IN    256
#define HID     128
#define NCLS    32
#define NEDGES  1600000
#define EPS_C   0.1f
#define GAMMA_C 0.1f

typedef __attribute__((ext_vector_type(8))) short short8;   // 8 bf16 = 4 VGPRs (MFMA A/B frag)
typedef __attribute__((ext_vector_type(4))) float floatx4;  // MFMA C/D frag

__device__ __forceinline__ float bf2f(unsigned short u) {
    union { unsigned int u; float f; } c;
    c.u = ((unsigned int)u) << 16;
    return c.f;
}
__device__ __forceinline__ unsigned short f2bf(float f) {
    union { float f; unsigned int u; } c; c.f = f;
    unsigned int u = c.u;
    u += 0x7FFFu + ((u >> 16) & 1u);   // round-to-nearest-even
    return (unsigned short)(u >> 16);
}

// Polymorphic scalar load: md=1 -> buffer is f32, md=0 -> bf16
__device__ __forceinline__ float ldf(const void* p, size_t i, int md) {
    return md ? ((const float*)p)[i] : bf2f(((const unsigned short*)p)[i]);
}
__device__ __forceinline__ short8 ld8(const void* p, size_t i, int md) {
    if (md) {
        const float* q = (const float*)p + i;
        short8 r;
#pragma unroll
        for (int j = 0; j < 8; ++j) r[j] = (short)f2bf(q[j]);
        return r;
    }
    return *(const short8*)((const unsigned short*)p + i);
}

// ---------------------------------------------------------------- dtype probe
__global__ void k_detect(const unsigned short* __restrict__ x, int* __restrict__ mode) {
    __shared__ int cnt;
    if (threadIdx.x == 0) cnt = 0;
    __syncthreads();
    float v = fabsf(bf2f(x[2 * threadIdx.x]));
    if (v > 1e4f || !isfinite(v)) atomicAdd(&cnt, 1);
    __syncthreads();
    if (threadIdx.x == 0) *mode = (cnt >= 8) ? 1 : 0;
}

// ---------------------------------------------------------------- CSR build
__global__ void k_zeroi(int* __restrict__ p, int n) {
    int i = blockIdx.x * blockDim.x + threadIdx.x;
    if (i < n) p[i] = 0;
}

__global__ void k_hist(const int* __restrict__ col, int* __restrict__ deg, int e) {
    int i = blockIdx.x * blockDim.x + threadIdx.x;
    if (i < e) atomicAdd(&deg[col[i]], 1);
}

// dinv[i] = rsqrt(deg[i] + 1)  (self-loop adds 1)
__global__ void k_dinv(const int* __restrict__ deg, float* __restrict__ dinv, int n) {
    int i = blockIdx.x * blockDim.x + threadIdx.x;
    if (i < n) dinv[i] = rsqrtf((float)deg[i] + 1.0f);
}

// Block-level exclusive scan (256/block), Hillis-Steele in LDS
__global__ void k_scan1(const int* __restrict__ deg, int* __restrict__ ex,
                        int* __restrict__ bsum, int n) {
    __shared__ int s[256];
    int i = blockIdx.x * 256 + threadIdx.x;
    int v = (i < n) ? deg[i] : 0;
    s[threadIdx.x] = v;
    __syncthreads();
#pragma unroll
    for (int off = 1; off < 256; off <<= 1) {
        int t = (threadIdx.x >= off) ? s[threadIdx.x - off] : 0;
        __syncthreads();
        s[threadIdx.x] += t;
        __syncthreads();
    }
    if (i < n) ex[i] = s[threadIdx.x] - v;        // exclusive
    if (threadIdx.x == 255) bsum[blockIdx.x] = s[255];
}

__global__ void k_scan2(int* __restrict__ bsum, int nb) {
    __shared__ int s[512];
    int v = (threadIdx.x < nb) ? bsum[threadIdx.x] : 0;
    s[threadIdx.x] = v;
    __syncthreads();
#pragma unroll
    for (int off = 1; off < 512; off <<= 1) {
        int t = (threadIdx.x >= off) ? s[threadIdx.x - off] : 0;
        __syncthreads();
        s[threadIdx.x] += t;
        __syncthreads();
    }
    if (threadIdx.x < nb) bsum[threadIdx.x] = s[threadIdx.x] - v;   // exclusive
}

__global__ void k_scan3(int* __restrict__ ex, const int* __restrict__ bsum,
                        int* __restrict__ cursor, int n) {
    int i = blockIdx.x * 256 + threadIdx.x;
    if (i < n) { int v = ex[i] + bsum[blockIdx.x]; ex[i] = v; cursor[i] = v; }
}

// Scatter edges into CSR order: srt[p] = source node of edge
__global__ void k_fill(const int* __restrict__ row, const int* __restrict__ col,
                       int* __restrict__ cursor, int* __restrict__ srt, int e) {
    int i = blockIdx.x * blockDim.x + threadIdx.x;
    if (i < e) {
        int p = atomicAdd(&cursor[col[i]], 1);
        srt[p] = row[i];
    }
}

// ---------------------------------------------------------------- weights
// aw = W - W^T - gamma*I  (row-major [d,d], bf16 out; W is an input -> poly)
__global__ void k_aw(const void* __restrict__ W, unsigned short* __restrict__ aw,
                     const int* __restrict__ dmode, int d) {
    int idx = blockIdx.x * blockDim.x + threadIdx.x;
    if (idx >= d * d) return;
    int md = dmode[0];
    int n = idx / d, k = idx - n * d;
    float v = ldf(W, n * d + k, md) - ldf(W, k * d + n, md) - ((n == k) ? GAMMA_C : 0.0f);
    aw[idx] = f2bf(v);
}

// ---------------------------------------------------------------- GEMM
// C[M,NC] = A[M,K] @ B[NC,K]^T, fp32 acc, bf16 out (internal).
// EPI: 0 = relu(acc+bias), 1 = acc, 2 = acc+bias,
//      3 = ASC: h + EPS*tanh(acc + agg + dinv^2*xw + bias)  (requires K==NC)
// agg is bf16 now. Cout may alias xw (per-element read-before-write in thread).
template<int K, int NC, int EPI, bool APOLY, bool BPOLY>
__global__ __launch_bounds__(256) void k_gemm(
    const void* A, const void* B, const void* bias,
    unsigned short* Cout,
    const unsigned short* agg, const unsigned short* xw, const float* dinv,
    const int* dmode, int M)
{
    constexpr int NT = NC / 16;
    const int md = dmode[0];
    const int wave = threadIdx.x >> 6;
    const int lane = threadIdx.x & 63;
    const int l15  = lane & 15;
    const int quad = lane >> 4;
    const int row_base = blockIdx.x * 64 + wave * 16;
    if (row_base >= M) return;

    int am = row_base + l15;
    if (am > M - 1) am = M - 1;           // clamp (dup read only, store guarded)

    floatx4 acc[NT];
#pragma unroll
    for (int t = 0; t < NT; ++t) acc[t] = (floatx4){0.f, 0.f, 0.f, 0.f};

#pragma unroll
    for (int kk = 0; kk < K; kk += 32) {
        short8 a = APOLY ? ld8(A, (size_t)am * K + kk + quad * 8, md)
                         : *(const short8*)((const unsigned short*)A + (size_t)am * K + kk + quad * 8);
#pragma unroll
        for (int t = 0; t < NT; ++t) {
            size_t bi = (size_t)(t * 16 + l15) * K + kk + quad * 8;
            short8 b = BPOLY ? ld8(B, bi, md)
                             : *(const short8*)((const unsigned short*)B + bi);
            acc[t] = __builtin_amdgcn_mfma_f32_16x16x32_bf16(a, b, acc[t], 0, 0, 0);
        }
    }

    // C/D layout: col = lane&15, row = quad*4 + reg  [m89-verified]
#pragma unroll
    for (int reg = 0; reg < 4; ++reg) {
        int rr = row_base + quad * 4 + reg;
        if (rr >= M) continue;
#pragma unroll
        for (int t = 0; t < NT; ++t) {
            int col = t * 16 + l15;
            float v = acc[t][reg];
            if (EPI == 0) {
                v += ldf(bias, col, md);
                v = v > 0.0f ? v : 0.0f;
            } else if (EPI == 2) {
                v += ldf(bias, col, md);
            } else if (EPI == 3) {
                float dv = dinv[rr];
                float z = v + bf2f(agg[(size_t)rr * NC + col])
                            + dv * dv * bf2f(xw[(size_t)rr * NC + col])
                            + ldf(bias, col, md);
                v = bf2f(((const unsigned short*)A)[(size_t)rr * K + col]) + EPS_C * tanhf(z);
            }
            Cout[(size_t)rr * NC + col] = f2bf(v);
        }
    }
}

// ---------------------------------------------------------------- gather
// agg[i] = dinv[i] * sum_{j in in(i)} dinv[src_j] * xw[src_j]
// LPN lanes per node, 2 bf16 features per lane (D = 2*LPN).
template<int D, int LPN>
__global__ __launch_bounds__(256) void k_gather(
    const int* __restrict__ srt, const int* __restrict__ rs,
    const int* __restrict__ cend,      // cursor after fill == row_start + deg
    const unsigned short* __restrict__ xw, const float* __restrict__ dinv,
    unsigned short* __restrict__ agg, int n)
{
    constexpr int NPB = 256 / LPN;     // nodes per block
    int node = blockIdx.x * NPB + threadIdx.x / LPN;
    int l = threadIdx.x % LPN;
    if (node >= n) return;
    int j = rs[node], end = cend[node];
    float a0 = 0.f, a1 = 0.f;
    for (; j < end; ++j) {
        int src = srt[j];
        float w = dinv[src];
        unsigned int pk = *(const unsigned int*)(xw + (size_t)src * D + l * 2);
        a0 += w * bf2f((unsigned short)(pk & 0xFFFFu));
        a1 += w * bf2f((unsigned short)(pk >> 16));
    }
    float dn = dinv[node];
    unsigned int out = (unsigned int)f2bf(dn * a0) | ((unsigned int)f2bf(dn * a1) << 16);
    *(unsigned int*)(agg + (size_t)node * D + l * 2) = out;
}

// ---------------------------------------------------------------- softmax
__global__ void k_logsoftmax(const unsigned short* __restrict__ h,
                             void* __restrict__ out,
                             const int* __restrict__ dmode, int n)
{
    int i = blockIdx.x * blockDim.x + threadIdx.x;
    if (i >= n) return;
    int md = dmode[0];
    float v[NCLS];
    float m = -1e30f;
#pragma unroll
    for (int j = 0; j < NCLS; ++j) { v[j] = bf2f(h[(size_t)i * NCLS + j]); m = fmaxf(m, v[j]); }
    float s = 0.0f;
#pragma unroll
    for (int j = 0; j < NCLS; ++j) s += expf(v[j] - m);
    float ls = m + logf(s);
#pragma unroll
    for (int j = 0; j < NCLS; ++j) {
        float r = v[j] - ls;
        if (md) ((float*)out)[(size_t)i * NCLS + j] = r;
        else    ((unsigned short*)out)[(size_t)i * NCLS + j] = f2bf(r);
    }
}

// ---------------------------------------------------------------- launch
extern "C" void kernel_launch(void* const* d_in, const int* in_sizes, int n_in,
                              void* d_out, int out_size, void* d_ws, size_t ws_size,
                              hipStream_t stream)
{
    const void* x      = d_in[0];
    const void* lin1_w = d_in[1];
    const void* lin1_b = d_in[2];
    const void* lin2_w = d_in[3];
    const void* lin2_b = d_in[4];
    const void* W1     = d_in[5];
    const void* phi1w  = d_in[6];
    const void* b1     = d_in[7];
    const void* W2     = d_in[8];
    const void* phi2w  = d_in[9];
    const void* b2     = d_in[10];
    const int* eidx    = (const int*)d_in[11];
    const int* erow = eidx;
    const int* ecol = eidx + NEDGES;

    // Workspace layout (high-water ~85.2 MB):
    //   [0)         dinv f32 [N]
    //   [400000)    dmode
    //   [401408)    aw1 bf16 128x128
    //   [435200)    aw2 bf16 32x32
    //   [440320)    deg   int [N]
    //   [840704)    row_start int [N]
    //   [1241088)   cursor int [N]  (after k_fill: row end offsets)
    //   [1641472)   bsum int [512]
    //   [1646592)   srt int [E]  (CSR source indices, 6.4MB)
    //   [8388608)   h1  bf16 [N,128]  (layer2: h3 [N,32])
    //   [+25.6MB)   xw1 bf16 [N,128] -> h2 in-place; layer2: xw2
    //   [+25.6MB)   agg1 bf16 [N,128] (layer2: agg2 [N,32], h4 at +6.4MB)
    char* ws = (char*)d_ws;
    float* dinv          = (float*)ws;
    int*   dmode         = (int*)(ws + 400000);
    unsigned short* aw1  = (unsigned short*)(ws + 401408);
    unsigned short* aw2  = (unsigned short*)(ws + 435200);
    int* deg             = (int*)(ws + 440320);
    int* row_start       = (int*)(ws + 840704);
    int* cursor          = (int*)(ws + 1241088);
    int* bsum            = (int*)(ws + 1641472);
    int* srt             = (int*)(ws + 1646592);
    size_t off = 8388608;
    unsigned short* h1   = (unsigned short*)(ws + off); off += (size_t)N_NODES * HID * 2;
    unsigned short* xw1  = (unsigned short*)(ws + off); off += (size_t)N_NODES * HID * 2;
    unsigned short* agg1 = (unsigned short*)(ws + off);
    unsigned short* h2   = xw1;            // in-place (EPI=3 read-before-write)
    unsigned short* h3   = h1;
    unsigned short* xw2  = xw1;
    unsigned short* agg2 = agg1;
    unsigned short* h4   = agg1 + (size_t)N_NODES * NCLS;

    const int GB = 256;
    const int NBLK = (N_NODES + 255) / 256;          // 391
    k_detect<<<1, 256, 0, stream>>>((const unsigned short*)x, dmode);

    // CSR build (also yields deg -> dinv)
    k_zeroi<<<NBLK, GB, 0, stream>>>(deg, N_NODES);
    k_hist<<<(NEDGES + GB - 1) / GB, GB, 0, stream>>>(ecol, deg, NEDGES);
    k_dinv<<<NBLK, GB, 0, stream>>>(deg, dinv, N_NODES);
    k_scan1<<<NBLK, 256, 0, stream>>>(deg, row_start, bsum, N_NODES);
    k_scan2<<<1, 512, 0, stream>>>(bsum, NBLK);
    k_scan3<<<NBLK, 256, 0, stream>>>(row_start, bsum, cursor, N_NODES);
    k_fill<<<(NEDGES + GB - 1) / GB, GB, 0, stream>>>(erow, ecol, cursor, srt, NEDGES);

    // antisymmetric weights
    k_aw<<<(HID * HID + GB - 1) / GB, GB, 0, stream>>>(W1, aw1, dmode, HID);
    k_aw<<<(NCLS * NCLS + GB - 1) / GB, GB, 0, stream>>>(W2, aw2, dmode, NCLS);

    const int gRows = (N_NODES + 63) / 64;
    // h1 = relu(x @ lin1_w.T + lin1_b)
    k_gemm<256, 128, 0, true, true><<<gRows, 256, 0, stream>>>(
        x, lin1_w, lin1_b, h1, nullptr, nullptr, nullptr, dmode, N_NODES);
    // xw1 = h1 @ phi1_w.T
    k_gemm<128, 128, 1, false, true><<<gRows, 256, 0, stream>>>(
        h1, phi1w, nullptr, xw1, nullptr, nullptr, nullptr, dmode, N_NODES);
    // agg1 = gather(norm * xw1)
    k_gather<128, 64><<<(N_NODES + 3) / 4, 256, 0, stream>>>(
        srt, row_start, cursor, xw1, dinv, agg1, N_NODES);
    // h2 = h1 + EPS*tanh(h1@aw1.T + agg1 + dinv^2*xw1 + b1)   (h2 aliases xw1)
    k_gemm<128, 128, 3, false, false><<<gRows, 256, 0, stream>>>(
        h1, aw1, b1, h2, agg1, xw1, dinv, dmode, N_NODES);
    // h3 = h2 @ lin2_w.T + lin2_b
    k_gemm<128, 32, 2, false, true><<<gRows, 256, 0, stream>>>(
        h2, lin2_w, lin2_b, h3, nullptr, nullptr, nullptr, dmode, N_NODES);
    // xw2 = h3 @ phi2_w.T
    k_gemm<32, 32, 1, false, true><<<gRows, 256, 0, stream>>>(
        h3, phi2w, nullptr, xw2, nullptr, nullptr, nullptr, dmode, N_NODES);
    // agg2 = gather(norm * xw2)
    k_gather<32, 16><<<(N_NODES + 15) / 16, 256, 0, stream>>>(
        srt, row_start, cursor, xw2, dinv, agg2, N_NODES);
    // h4 = h3 + EPS*tanh(h3@aw2.T + agg2 + dinv^2*xw2 + b2)
    k_gemm<32, 32, 3, false, false><<<gRows, 256, 0, stream>>>(
        h3, aw2, b2, h4, agg2, xw2, dinv, dmode, N_NODES);
    // out = log_softmax(h4)
    k_logsoftmax<<<(N_NODES + GB - 1) / GB, GB, 0, stream>>>(h4, d_out, dmode, N_NODES);
}

// Round 4
// 740.174 us; speedup vs baseline: 10.0918x; 1.1796x over previous
//
#include <hip/hip_runtime.h>
#include <hip/hip_bf16.h>
#include <math.h>

// Problem constants (from reference)
#define N_NODES 100000
#define F_IN    256
#define HID     128
#define NCLS    32
#define NEDGES  1600000
#define EPS_C   0.1f
#define GAMMA_C 0.1f

typedef __attribute__((ext_vector_type(8))) short short8;   // 8 bf16 = 4 VGPRs (MFMA A/B frag)
typedef __attribute__((ext_vector_type(4))) float floatx4;  // MFMA C/D frag

__device__ __forceinline__ float bf2f(unsigned short u) {
    union { unsigned int u; float f; } c;
    c.u = ((unsigned int)u) << 16;
    return c.f;
}
__device__ __forceinline__ unsigned short f2bf(float f) {
    union { float f; unsigned int u; } c; c.f = f;
    unsigned int u = c.u;
    u += 0x7FFFu + ((u >> 16) & 1u);   // round-to-nearest-even
    return (unsigned short)(u >> 16);
}

// Polymorphic scalar load: md=1 -> buffer is f32, md=0 -> bf16
__device__ __forceinline__ float ldf(const void* p, size_t i, int md) {
    return md ? ((const float*)p)[i] : bf2f(((const unsigned short*)p)[i]);
}
__device__ __forceinline__ short8 ld8(const void* p, size_t i, int md) {
    if (md) {
        const float* q = (const float*)p + i;
        short8 r;
#pragma unroll
        for (int j = 0; j < 8; ++j) r[j] = (short)f2bf(q[j]);
        return r;
    }
    return *(const short8*)((const unsigned short*)p + i);
}

// ---------------------------------------------------------------- dtype probe
__global__ void k_detect(const unsigned short* __restrict__ x, int* __restrict__ mode) {
    __shared__ int cnt;
    if (threadIdx.x == 0) cnt = 0;
    __syncthreads();
    float v = fabsf(bf2f(x[2 * threadIdx.x]));
    if (v > 1e4f || !isfinite(v)) atomicAdd(&cnt, 1);
    __syncthreads();
    if (threadIdx.x == 0) *mode = (cnt >= 8) ? 1 : 0;
}

// ---------------------------------------------------------------- CSR build
__global__ void k_zeroi(int* __restrict__ p, int n) {
    int i = blockIdx.x * blockDim.x + threadIdx.x;
    if (i < n) p[i] = 0;
}

__global__ void k_hist(const int* __restrict__ col, int* __restrict__ deg, int e) {
    int i = blockIdx.x * blockDim.x + threadIdx.x;
    if (i < e) atomicAdd(&deg[col[i]], 1);
}

__global__ void k_dinv(const int* __restrict__ deg, float* __restrict__ dinv, int n) {
    int i = blockIdx.x * blockDim.x + threadIdx.x;
    if (i < n) dinv[i] = rsqrtf((float)deg[i] + 1.0f);
}

__global__ void k_scan1(const int* __restrict__ deg, int* __restrict__ ex,
                        int* __restrict__ bsum, int n) {
    __shared__ int s[256];
    int i = blockIdx.x * 256 + threadIdx.x;
    int v = (i < n) ? deg[i] : 0;
    s[threadIdx.x] = v;
    __syncthreads();
#pragma unroll
    for (int off = 1; off < 256; off <<= 1) {
        int t = (threadIdx.x >= off) ? s[threadIdx.x - off] : 0;
        __syncthreads();
        s[threadIdx.x] += t;
        __syncthreads();
    }
    if (i < n) ex[i] = s[threadIdx.x] - v;
    if (threadIdx.x == 255) bsum[blockIdx.x] = s[255];
}

__global__ void k_scan2(int* __restrict__ bsum, int nb) {
    __shared__ int s[512];
    int v = (threadIdx.x < nb) ? bsum[threadIdx.x] : 0;
    s[threadIdx.x] = v;
    __syncthreads();
#pragma unroll
    for (int off = 1; off < 512; off <<= 1) {
        int t = (threadIdx.x >= off) ? s[threadIdx.x - off] : 0;
        __syncthreads();
        s[threadIdx.x] += t;
        __syncthreads();
    }
    if (threadIdx.x < nb) bsum[threadIdx.x] = s[threadIdx.x] - v;
}

__global__ void k_scan3(int* __restrict__ ex, const int* __restrict__ bsum,
                        int* __restrict__ cursor, int n) {
    int i = blockIdx.x * 256 + threadIdx.x;
    if (i < n) { int v = ex[i] + bsum[blockIdx.x]; ex[i] = v; cursor[i] = v; }
}

__global__ void k_fill(const int* __restrict__ row, const int* __restrict__ col,
                       int* __restrict__ cursor, int* __restrict__ srt, int e) {
    int i = blockIdx.x * blockDim.x + threadIdx.x;
    if (i < e) {
        int p = atomicAdd(&cursor[col[i]], 1);
        srt[p] = row[i];
    }
}

// ---------------------------------------------------------------- weights
__global__ void k_aw(const void* __restrict__ W, unsigned short* __restrict__ aw,
                     const int* __restrict__ dmode, int d) {
    int idx = blockIdx.x * blockDim.x + threadIdx.x;
    if (idx >= d * d) return;
    int md = dmode[0];
    int n = idx / d, k = idx - n * d;
    float v = ldf(W, n * d + k, md) - ldf(W, k * d + n, md) - ((n == k) ? GAMMA_C : 0.0f);
    aw[idx] = f2bf(v);
}

// ---------------------------------------------------------------- GEMM v2
// C[M,NC] = A[M,K] @ B[NC,K]^T. B staged in padded LDS (free 2-way bank alias).
// 4 waves/block, 4 row-tiles/wave -> 256 rows/block, NT = NC/16 col tiles.
// EPI: 0 relu(acc+bias) | 2 acc+bias | 5 dinv[r]*acc (pre-scaled xw for gather)
//      3 ASC: h + EPS*tanh(acc + agg + dinv*xws + bias)          (K==NC)
//      4 ASC + fused log_softmax -> opout (poly dtype)           (K==NC==32)
template<int K, int NC, int EPI, bool APOLY, bool BPOLY>
__global__ __launch_bounds__(256) void k_gemm2(
    const void* A, const void* B, const void* bias,
    unsigned short* Cout,
    const unsigned short* agg, const unsigned short* xw, const float* dinv,
    const int* dmode, void* opout, int M)
{
    constexpr int KP = K + 8;
    constexpr int NT = NC / 16;
    constexpr int RT = 4;
    __shared__ __align__(16) unsigned short sB[NC * KP];
    const int md = dmode[0];

    for (int base = threadIdx.x * 8; base < NC * K; base += 2048) {
        int r = base / K, c = base - r * K;
        if (BPOLY && md) {
            const float* q = (const float*)B + base;
#pragma unroll
            for (int j = 0; j < 8; ++j) sB[r * KP + c + j] = f2bf(q[j]);
        } else {
            *(short8*)(sB + r * KP + c) = *(const short8*)((const unsigned short*)B + base);
        }
    }
    __syncthreads();

    const int lane = threadIdx.x & 63;
    const int wave = threadIdx.x >> 6;
    const int l15  = lane & 15;
    const int quad = lane >> 4;
    const int row0 = blockIdx.x * 256 + wave * 64;
    if (row0 >= M) return;

    int am[RT];
#pragma unroll
    for (int rt = 0; rt < RT; ++rt) {
        int r = row0 + rt * 16 + l15;
        am[rt] = r < M ? r : M - 1;
    }

    floatx4 acc[RT][NT];
#pragma unroll
    for (int rt = 0; rt < RT; ++rt)
#pragma unroll
        for (int t = 0; t < NT; ++t) acc[rt][t] = (floatx4){0.f, 0.f, 0.f, 0.f};

#pragma unroll 2
    for (int kk = 0; kk < K; kk += 32) {
        short8 a[RT];
#pragma unroll
        for (int rt = 0; rt < RT; ++rt)
            a[rt] = APOLY ? ld8(A, (size_t)am[rt] * K + kk + quad * 8, md)
                          : *(const short8*)((const unsigned short*)A + (size_t)am[rt] * K + kk + quad * 8);
        short8 b[NT];
#pragma unroll
        for (int t = 0; t < NT; ++t)
            b[t] = *(const short8*)(sB + (t * 16 + l15) * KP + kk + quad * 8);
#pragma unroll
        for (int rt = 0; rt < RT; ++rt)
#pragma unroll
            for (int t = 0; t < NT; ++t)
                acc[rt][t] = __builtin_amdgcn_mfma_f32_16x16x32_bf16(a[rt], b[t], acc[rt][t], 0, 0, 0);
    }

    const unsigned short* Ares = (const unsigned short*)A;
    // C/D layout: col = lane&15, row = quad*4 + reg  [m89-verified]
#pragma unroll
    for (int rt = 0; rt < RT; ++rt) {
#pragma unroll
        for (int reg = 0; reg < 4; ++reg) {
            int rr = row0 + rt * 16 + quad * 4 + reg;
            if (EPI == 4) {
                int rrc = rr < M ? rr : M - 1;
                float dv = dinv[rrc];
                float val[NT];
#pragma unroll
                for (int t = 0; t < NT; ++t) {
                    int col = t * 16 + l15;
                    float z = acc[rt][t][reg]
                            + bf2f(agg[(size_t)rrc * NC + col])
                            + dv * bf2f(xw[(size_t)rrc * NC + col])
                            + ldf(bias, col, md);
                    val[t] = bf2f(Ares[(size_t)rrc * K + col]) + EPS_C * tanhf(z);
                }
                float m = val[0];
#pragma unroll
                for (int t = 1; t < NT; ++t) m = fmaxf(m, val[t]);
#pragma unroll
                for (int msk = 1; msk < 16; msk <<= 1) m = fmaxf(m, __shfl_xor(m, msk));
                float s = 0.f;
#pragma unroll
                for (int t = 0; t < NT; ++t) s += expf(val[t] - m);
#pragma unroll
                for (int msk = 1; msk < 16; msk <<= 1) s += __shfl_xor(s, msk);
                float ls = m + logf(s);
                if (rr < M) {
#pragma unroll
                    for (int t = 0; t < NT; ++t) {
                        int col = t * 16 + l15;
                        float r = val[t] - ls;
                        if (md) ((float*)opout)[(size_t)rr * NC + col] = r;
                        else    ((unsigned short*)opout)[(size_t)rr * NC + col] = f2bf(r);
                    }
                }
            } else {
                if (rr >= M) continue;
#pragma unroll
                for (int t = 0; t < NT; ++t) {
                    int col = t * 16 + l15;
                    float v = acc[rt][t][reg];
                    if (EPI == 0) { v += ldf(bias, col, md); v = v > 0.f ? v : 0.f; }
                    else if (EPI == 2) { v += ldf(bias, col, md); }
                    else if (EPI == 5) { v *= dinv[rr]; }
                    else if (EPI == 3) {
                        float dv = dinv[rr];
                        float z = v + bf2f(agg[(size_t)rr * NC + col])
                                + dv * bf2f(xw[(size_t)rr * NC + col])
                                + ldf(bias, col, md);
                        v = bf2f(Ares[(size_t)rr * K + col]) + EPS_C * tanhf(z);
                    }
                    Cout[(size_t)rr * NC + col] = f2bf(v);
                }
            }
        }
    }
}

// ---------------------------------------------------------------- fused lin2+phi2
// h3 = h2 @ lin2_w.T + lin2_b ; xws2 = dinv * (h3 @ phi2_w.T)
// h3 tile round-trips through LDS into MFMA A-operand layout.
__global__ __launch_bounds__(256) void k_lin2phi2(
    const unsigned short* __restrict__ A, const void* __restrict__ B1,
    const void* __restrict__ bias, const void* __restrict__ B2,
    unsigned short* __restrict__ h3, unsigned short* __restrict__ xws2,
    const float* __restrict__ dinv, const int* __restrict__ dmode, int M)
{
    constexpr int K1 = 128, KP1 = 136, KP2 = 40;
    __shared__ __align__(16) unsigned short sB1[32 * KP1];
    __shared__ __align__(16) unsigned short sB2[32 * KP2];
    __shared__ __align__(16) unsigned short sT[256 * KP2];
    const int md = dmode[0];

    for (int base = threadIdx.x * 8; base < 32 * K1; base += 2048) {
        int r = base / K1, c = base - r * K1;
        if (md) {
            const float* q = (const float*)B1 + base;
#pragma unroll
            for (int j = 0; j < 8; ++j) sB1[r * KP1 + c + j] = f2bf(q[j]);
        } else {
            *(short8*)(sB1 + r * KP1 + c) = *(const short8*)((const unsigned short*)B1 + base);
        }
    }
    for (int base = threadIdx.x * 8; base < 32 * 32; base += 2048) {
        int r = base / 32, c = base - r * 32;
        if (md) {
            const float* q = (const float*)B2 + base;
#pragma unroll
            for (int j = 0; j < 8; ++j) sB2[r * KP2 + c + j] = f2bf(q[j]);
        } else {
            *(short8*)(sB2 + r * KP2 + c) = *(const short8*)((const unsigned short*)B2 + base);
        }
    }
    __syncthreads();

    const int lane = threadIdx.x & 63;
    const int wave = threadIdx.x >> 6;
    const int l15  = lane & 15;
    const int quad = lane >> 4;
    const int row0 = blockIdx.x * 256 + wave * 64;

    int am[4];
#pragma unroll
    for (int rt = 0; rt < 4; ++rt) {
        int r = row0 + rt * 16 + l15;
        am[rt] = r < M ? r : M - 1;
    }

    floatx4 acc[4][2];
#pragma unroll
    for (int rt = 0; rt < 4; ++rt) { acc[rt][0] = (floatx4){0,0,0,0}; acc[rt][1] = (floatx4){0,0,0,0}; }

#pragma unroll
    for (int kk = 0; kk < K1; kk += 32) {
#pragma unroll
        for (int rt = 0; rt < 4; ++rt) {
            short8 a = *(const short8*)(A + (size_t)am[rt] * K1 + kk + quad * 8);
#pragma unroll
            for (int t = 0; t < 2; ++t) {
                short8 b = *(const short8*)(sB1 + (t * 16 + l15) * KP1 + kk + quad * 8);
                acc[rt][t] = __builtin_amdgcn_mfma_f32_16x16x32_bf16(a, b, acc[rt][t], 0, 0, 0);
            }
        }
    }
    // epilogue 1: bias add, store h3 (global + LDS tile)
#pragma unroll
    for (int rt = 0; rt < 4; ++rt)
#pragma unroll
        for (int reg = 0; reg < 4; ++reg) {
            int rr = row0 + rt * 16 + quad * 4 + reg;
            int lr = wave * 64 + rt * 16 + quad * 4 + reg;
#pragma unroll
            for (int t = 0; t < 2; ++t) {
                int col = t * 16 + l15;
                unsigned short hv = f2bf(acc[rt][t][reg] + ldf(bias, col, md));
                sT[lr * KP2 + col] = hv;
                if (rr < M) h3[(size_t)rr * 32 + col] = hv;
            }
        }
    __syncthreads();

    // stage 2: xws2 = dinv * (h3 @ phi2_w.T), K=32 single MFMA step
    floatx4 a2[4][2];
#pragma unroll
    for (int rt = 0; rt < 4; ++rt) {
        short8 a = *(const short8*)(sT + (wave * 64 + rt * 16 + l15) * KP2 + quad * 8);
#pragma unroll
        for (int t = 0; t < 2; ++t) {
            short8 b = *(const short8*)(sB2 + (t * 16 + l15) * KP2 + quad * 8);
            a2[rt][t] = __builtin_amdgcn_mfma_f32_16x16x32_bf16(a, b, (floatx4){0,0,0,0}, 0, 0, 0);
        }
    }
#pragma unroll
    for (int rt = 0; rt < 4; ++rt)
#pragma unroll
        for (int reg = 0; reg < 4; ++reg) {
            int rr = row0 + rt * 16 + quad * 4 + reg;
            if (rr >= M) continue;
            float dv = dinv[rr];
#pragma unroll
            for (int t = 0; t < 2; ++t)
                xws2[(size_t)rr * 32 + t * 16 + l15] = f2bf(dv * a2[rt][t][reg]);
        }
}

// ---------------------------------------------------------------- gather
// agg[i] = dinv[i] * sum_{j in in(i)} xws[src_j]   (xws pre-scaled by dinv[src])
template<int D, int LPN>
__global__ __launch_bounds__(256) void k_gather(
    const int* __restrict__ srt, const int* __restrict__ rs,
    const int* __restrict__ cend,
    const unsigned short* __restrict__ xws, const float* __restrict__ dinv,
    unsigned short* __restrict__ agg, int n)
{
    constexpr int NPB = 256 / LPN;
    int node = blockIdx.x * NPB + threadIdx.x / LPN;
    int l = threadIdx.x % LPN;
    if (node >= n) return;
    int j = rs[node], end = cend[node];
    float a0 = 0.f, a1 = 0.f;
    for (; j + 1 < end; j += 2) {
        int s0 = srt[j], s1 = srt[j + 1];
        unsigned int p0 = *(const unsigned int*)(xws + (size_t)s0 * D + l * 2);
        unsigned int p1 = *(const unsigned int*)(xws + (size_t)s1 * D + l * 2);
        a0 += bf2f((unsigned short)(p0 & 0xFFFFu)) + bf2f((unsigned short)(p1 & 0xFFFFu));
        a1 += bf2f((unsigned short)(p0 >> 16))     + bf2f((unsigned short)(p1 >> 16));
    }
    if (j < end) {
        int s0 = srt[j];
        unsigned int p0 = *(const unsigned int*)(xws + (size_t)s0 * D + l * 2);
        a0 += bf2f((unsigned short)(p0 & 0xFFFFu));
        a1 += bf2f((unsigned short)(p0 >> 16));
    }
    float dn = dinv[node];
    unsigned int out = (unsigned int)f2bf(dn * a0) | ((unsigned int)f2bf(dn * a1) << 16);
    *(unsigned int*)(agg + (size_t)node * D + l * 2) = out;
}

// ---------------------------------------------------------------- launch
extern "C" void kernel_launch(void* const* d_in, const int* in_sizes, int n_in,
                              void* d_out, int out_size, void* d_ws, size_t ws_size,
                              hipStream_t stream)
{
    const void* x      = d_in[0];
    const void* lin1_w = d_in[1];
    const void* lin1_b = d_in[2];
    const void* lin2_w = d_in[3];
    const void* lin2_b = d_in[4];
    const void* W1     = d_in[5];
    const void* phi1w  = d_in[6];
    const void* b1     = d_in[7];
    const void* W2     = d_in[8];
    const void* phi2w  = d_in[9];
    const void* b2     = d_in[10];
    const int* eidx    = (const int*)d_in[11];
    const int* erow = eidx;
    const int* ecol = eidx + NEDGES;

    // Workspace (high-water ~85.2 MB — R1 failed at 128.5MB, keep <= ~85MB):
    char* ws = (char*)d_ws;
    float* dinv          = (float*)ws;
    int*   dmode         = (int*)(ws + 400000);
    unsigned short* aw1  = (unsigned short*)(ws + 401408);
    unsigned short* aw2  = (unsigned short*)(ws + 435200);
    int* deg             = (int*)(ws + 440320);
    int* row_start       = (int*)(ws + 840704);
    int* cursor          = (int*)(ws + 1241088);
    int* bsum            = (int*)(ws + 1641472);
    int* srt             = (int*)(ws + 1646592);
    unsigned short* h1   = (unsigned short*)(ws + 8388608);           // [N,128]
    unsigned short* xws1 = h1 + (size_t)N_NODES * HID;                // [N,128]
    unsigned short* agg1 = xws1 + (size_t)N_NODES * HID;              // [N,128]
    unsigned short* h2   = xws1;   // EPI3 in-place (read-before-write per thread)
    unsigned short* h3   = h1;     // h1 dead after EPI3
    unsigned short* xws2 = agg1;   // agg1 dead after EPI3
    unsigned short* agg2 = agg1 + (size_t)N_NODES * NCLS;

    const int GB = 256;
    const int NBLK = (N_NODES + 255) / 256;          // 391
    k_detect<<<1, 256, 0, stream>>>((const unsigned short*)x, dmode);

    // CSR build
    k_zeroi<<<NBLK, GB, 0, stream>>>(deg, N_NODES);
    k_hist<<<(NEDGES + GB - 1) / GB, GB, 0, stream>>>(ecol, deg, NEDGES);
    k_dinv<<<NBLK, GB, 0, stream>>>(deg, dinv, N_NODES);
    k_scan1<<<NBLK, 256, 0, stream>>>(deg, row_start, bsum, N_NODES);
    k_scan2<<<1, 512, 0, stream>>>(bsum, NBLK);
    k_scan3<<<NBLK, 256, 0, stream>>>(row_start, bsum, cursor, N_NODES);
    k_fill<<<(NEDGES + GB - 1) / GB, GB, 0, stream>>>(erow, ecol, cursor, srt, NEDGES);

    // antisymmetric weights
    k_aw<<<(HID * HID + GB - 1) / GB, GB, 0, stream>>>(W1, aw1, dmode, HID);
    k_aw<<<(NCLS * NCLS + GB - 1) / GB, GB, 0, stream>>>(W2, aw2, dmode, NCLS);

    // h1 = relu(x @ lin1_w.T + lin1_b)
    k_gemm2<256, 128, 0, true, true><<<NBLK, 256, 0, stream>>>(
        x, lin1_w, lin1_b, h1, nullptr, nullptr, nullptr, dmode, nullptr, N_NODES);
    // xws1 = dinv * (h1 @ phi1_w.T)
    k_gemm2<128, 128, 5, false, true><<<NBLK, 256, 0, stream>>>(
        h1, phi1w, nullptr, xws1, nullptr, nullptr, dinv, dmode, nullptr, N_NODES);
    // agg1 = dinv * gather(xws1)
    k_gather<128, 64><<<(N_NODES + 3) / 4, 256, 0, stream>>>(
        srt, row_start, cursor, xws1, dinv, agg1, N_NODES);
    // h2 = h1 + EPS*tanh(h1@aw1.T + agg1 + dinv*xws1 + b1)   (in-place on xws1)
    k_gemm2<128, 128, 3, false, false><<<NBLK, 256, 0, stream>>>(
        h1, aw1, b1, h2, agg1, xws1, dinv, dmode, nullptr, N_NODES);
    // h3 = h2@lin2_w.T + lin2_b ; xws2 = dinv*(h3@phi2_w.T)   (fused)
    k_lin2phi2<<<NBLK, 256, 0, stream>>>(h2, lin2_w, lin2_b, phi2w, h3, xws2, dinv, dmode, N_NODES);
    // agg2 = dinv * gather(xws2)
    k_gather<32, 16><<<(N_NODES + 15) / 16, 256, 0, stream>>>(
        srt, row_start, cursor, xws2, dinv, agg2, N_NODES);
    // out = log_softmax(h3 + EPS*tanh(h3@aw2.T + agg2 + dinv*xws2 + b2))  (fused)
    k_gemm2<32, 32, 4, false, false><<<NBLK, 256, 0, stream>>>(
        h3, aw2, b2, nullptr, agg2, xws2, dinv, dmode, d_out, N_NODES);
}